// Round 1
// baseline (70.889 us; speedup 1.0000x reference)
//
#include <hip/hip_runtime.h>

// Problem constants (from reference)
#define B_    8
#define H_    512
#define W_    512
#define KS_   3
#define KK_   9
#define COUT_ 3
#define HO_   510
#define WO_   510

__global__ __launch_bounds__(256) void dcn_fwd_kernel(
    const float* __restrict__ x,       // [B,1,H,W]
    const float* __restrict__ offset,  // [B,2*KK,HO,WO]  (ch = 2*kk+{0:dy,1:dx})
    const float* __restrict__ mask,    // [B,KK,HO,WO]
    const float* __restrict__ weight,  // [COUT,1,KS,KS]
    const float* __restrict__ bias,    // [COUT]
    float* __restrict__ out)           // [B,COUT,HO,WO]
{
    const int total = B_ * HO_ * WO_;
    int idx = blockIdx.x * blockDim.x + threadIdx.x;
    if (idx >= total) return;

    const int wo = idx % WO_;
    int t = idx / WO_;
    const int ho = t % HO_;
    const int b  = t / HO_;

    const size_t planeO = (size_t)HO_ * WO_;
    const float* xb   = x + (size_t)b * (H_ * W_);
    const float* offb = offset + (size_t)b * (2 * KK_) * planeO + (size_t)ho * WO_ + wo;
    const float* mb   = mask   + (size_t)b * KK_ * planeO       + (size_t)ho * WO_ + wo;

    // weight/bias -> registers (same address across lanes: one cache line, broadcast)
    float w0[KK_], w1[KK_], w2[KK_];
    #pragma unroll
    for (int k = 0; k < KK_; ++k) {
        w0[k] = weight[0 * KK_ + k];
        w1[k] = weight[1 * KK_ + k];
        w2[k] = weight[2 * KK_ + k];
    }
    const float b0 = bias[0], b1 = bias[1], b2 = bias[2];

    float acc0 = 0.f, acc1 = 0.f, acc2 = 0.f;

    #pragma unroll
    for (int kk = 0; kk < KK_; ++kk) {
        const float dy = offb[(size_t)(2 * kk)     * planeO];
        const float dx = offb[(size_t)(2 * kk + 1) * planeO];
        const float m  = mb [(size_t)kk            * planeO];

        const float py = (float)(ho + (kk / KS_)) + dy;
        const float px = (float)(wo + (kk % KS_)) + dx;

        const float y0f = floorf(py);
        const float x0f = floorf(px);
        const float ly  = py - y0f;
        const float lx  = px - x0f;
        const float y1f = y0f + 1.0f;
        const float x1f = x0f + 1.0f;

        // validity on UNCLIPPED float corner coords (reference semantics)
        const float vy0 = (y0f >= 0.0f && y0f <= (float)(H_ - 1)) ? 1.0f : 0.0f;
        const float vy1 = (y1f >= 0.0f && y1f <= (float)(H_ - 1)) ? 1.0f : 0.0f;
        const float vx0 = (x0f >= 0.0f && x0f <= (float)(W_ - 1)) ? 1.0f : 0.0f;
        const float vx1 = (x1f >= 0.0f && x1f <= (float)(W_ - 1)) ? 1.0f : 0.0f;

        // clamped integer indices (always in-bounds loads)
        int yi0 = (int)y0f; yi0 = yi0 < 0 ? 0 : (yi0 > H_ - 1 ? H_ - 1 : yi0);
        int yi1 = (int)y1f; yi1 = yi1 < 0 ? 0 : (yi1 > H_ - 1 ? H_ - 1 : yi1);
        int xi0 = (int)x0f; xi0 = xi0 < 0 ? 0 : (xi0 > W_ - 1 ? W_ - 1 : xi0);
        int xi1 = (int)x1f; xi1 = xi1 < 0 ? 0 : (xi1 > W_ - 1 ? W_ - 1 : xi1);

        const float v00 = xb[yi0 * W_ + xi0] * (vy0 * vx0);
        const float v01 = xb[yi0 * W_ + xi1] * (vy0 * vx1);
        const float v10 = xb[yi1 * W_ + xi0] * (vy1 * vx0);
        const float v11 = xb[yi1 * W_ + xi1] * (vy1 * vx1);

        const float val = v00 * (1.0f - ly) * (1.0f - lx)
                        + v01 * (1.0f - ly) * lx
                        + v10 * ly * (1.0f - lx)
                        + v11 * ly * lx;

        const float s = val * m;
        acc0 = fmaf(w0[kk], s, acc0);
        acc1 = fmaf(w1[kk], s, acc1);
        acc2 = fmaf(w2[kk], s, acc2);
    }

    const size_t obase = (size_t)b * COUT_ * planeO + (size_t)ho * WO_ + wo;
    out[obase]              = acc0 + b0;
    out[obase + planeO]     = acc1 + b1;
    out[obase + 2 * planeO] = acc2 + b2;
}

extern "C" void kernel_launch(void* const* d_in, const int* in_sizes, int n_in,
                              void* d_out, int out_size, void* d_ws, size_t ws_size,
                              hipStream_t stream) {
    const float* x      = (const float*)d_in[0];
    const float* offset = (const float*)d_in[1];
    const float* mask   = (const float*)d_in[2];
    const float* weight = (const float*)d_in[3];
    const float* bias   = (const float*)d_in[4];
    float* out = (float*)d_out;

    const int total = B_ * HO_ * WO_;
    const int block = 256;
    const int grid  = (total + block - 1) / block;
    dcn_fwd_kernel<<<grid, block, 0, stream>>>(x, offset, mask, weight, bias, out);
}